// Round 1
// 10283.386 us; speedup vs baseline: 1.0454x; 1.0454x over previous
//
#include <hip/hip_runtime.h>
#include <hip/hip_bf16.h>
#include <math.h>

#define B 32
#define T 64
#define S 256
#define H 512
#define E 256
#define V 32000
#define NH 8
#define HD 64
#define TS 63          // steps (T-1)
#define NR 2016        // TS*B rows
#define G3 1536        // 3*H
#define GRID_REC 256

typedef short bf16x8 __attribute__((ext_vector_type(8)));
typedef float f32x4 __attribute__((ext_vector_type(4)));

__device__ __forceinline__ unsigned short f2bf(float f) {
    union { float f; unsigned u; } v; v.f = f;
    unsigned r = v.u + 0x7FFF + ((v.u >> 16) & 1);   // RNE
    return (unsigned short)(r >> 16);
}
__device__ __forceinline__ float clipf(float v, float lo, float hi) {
    return fminf(hi, fmaxf(lo, v));
}
__device__ __forceinline__ float sigf(float x) { return 1.0f / (1.0f + __expf(-x)); }

// ---- agent-scope (sc1) accessors: bypass the non-coherent per-XCD L2 for
// ---- ONLY the cross-workgroup vectors, so everything else stays L2-resident.
__device__ __forceinline__ void stA(float* p, float v) {
    __hip_atomic_store(p, v, __ATOMIC_RELAXED, __HIP_MEMORY_SCOPE_AGENT);
}
__device__ __forceinline__ unsigned long long ldA64(const void* p) {
    return __hip_atomic_load((unsigned long long*)p, __ATOMIC_RELAXED, __HIP_MEMORY_SCOPE_AGENT);
}

// ---------------- prolog kernels ----------------

__global__ void k_zero_t0(float* out) {
    int idx = blockIdx.x * 256 + threadIdx.x;        // over B*V/4
    int n = B * V / 4;
    if (idx < n) {
        int b = idx / (V / 4);
        int v4 = idx % (V / 4);
        float4* p = (float4*)(out + (size_t)b * T * V) + v4;
        *p = make_float4(0.f, 0.f, 0.f, 0.f);
    }
}

// h0c/h1c in [j][b] layout (j*32+b); h1r row-major [b][j]
__global__ void k_init_h(const float* dec, float* h0c, float* h1c, float* h1r) {
    int i = blockIdx.x * 256 + threadIdx.x;
    if (i < B * H) {
        int b = i >> 9, j = i & 511;
        float v = clipf(dec[i], -10.f, 10.f);
        h0c[j * 32 + b] = v; h1c[j * 32 + b] = v; h1r[i] = v;
    }
}

// Kh (clipped, transposed to [b][i][s]) and Vh ([b][s][i])
__global__ __launch_bounds__(256) void k_kv(const float* __restrict__ enc,
        const float* __restrict__ wk, const float* __restrict__ bk,
        const float* __restrict__ wv, const float* __restrict__ bv,
        float* __restrict__ kht, float* __restrict__ vh) {
    __shared__ float x[H];
    int row = blockIdx.x; int b = row / S; int s = row % S;
    const float* er = enc + (size_t)row * H;
    for (int i = threadIdx.x; i < H; i += 256) x[i] = er[i];
    __syncthreads();
    for (int i = threadIdx.x; i < H; i += 256) {
        const float* wr  = wk + (size_t)i * H;
        const float* wr2 = wv + (size_t)i * H;
        float aK = bk[i], aV = bv[i];
        for (int k = 0; k < H; k += 4) {
            float4 xv = *(const float4*)(x + k);
            float4 a  = *(const float4*)(wr + k);
            float4 c  = *(const float4*)(wr2 + k);
            aK += xv.x*a.x + xv.y*a.y + xv.z*a.z + xv.w*a.w;
            aV += xv.x*c.x + xv.y*c.y + xv.z*c.z + xv.w*c.w;
        }
        kht[((size_t)b * H + i) * S + s] = clipf(aK, -100.f, 100.f);
        vh[((size_t)b * S + s) * H + i] = aV;
    }
}

// GIE0[(t*1536+j)*32+b] = b_ih0[j] + emb(t,b) . w_ih0[j, 0:512]
__global__ __launch_bounds__(256) void k_gie(const int* __restrict__ tgt,
        const float* __restrict__ embt, const float* __restrict__ wep,
        const float* __restrict__ bep, const float* __restrict__ wih0,
        const float* __restrict__ bih0, float* __restrict__ gie) {
    __shared__ float er[E];
    __shared__ float xf[H];
    int r = blockIdx.x; int t = r >> 5; int b = r & 31;
    int tok = tgt[b * T + t];
    const float* em = embt + (size_t)tok * E;
    for (int i = threadIdx.x; i < E; i += 256) er[i] = em[i];
    __syncthreads();
    for (int i = threadIdx.x; i < H; i += 256) {
        const float* wr = wep + (size_t)i * E;
        float acc = bep[i];
        for (int k = 0; k < E; k += 4) {
            float4 xv = *(const float4*)(er + k);
            float4 a  = *(const float4*)(wr + k);
            acc += xv.x*a.x + xv.y*a.y + xv.z*a.z + xv.w*a.w;
        }
        xf[i] = acc;
    }
    __syncthreads();
    for (int j = threadIdx.x; j < G3; j += 256) {
        const float* wr = wih0 + (size_t)j * (2 * H);   // emb part = cols 0..511
        float acc = bih0[j];
        for (int k = 0; k < H; k += 4) {
            float4 xv = *(const float4*)(xf + k);
            float4 a  = *(const float4*)(wr + k);
            acc += xv.x*a.x + xv.y*a.y + xv.z*a.z + xv.w*a.w;
        }
        gie[((size_t)t * G3 + j) * 32 + b] = acc;
    }
}

__global__ void k_cvt(const float* __restrict__ wo1, const float* __restrict__ wo2,
                      unsigned short* __restrict__ w1b, unsigned short* __restrict__ w2b) {
    size_t idx = (size_t)blockIdx.x * 256 + threadIdx.x;
    size_t stride = (size_t)gridDim.x * 256;
    size_t n1 = (size_t)H * 2 * H;
    size_t n2 = (size_t)V * H;
    for (size_t i = idx; i < n1; i += stride) w1b[i] = f2bf(wo1[i]);
    for (size_t i = idx; i < n2; i += stride) w2b[i] = f2bf(wo2[i]);
}

// ---------------- persistent recurrence kernel ----------------

// No agent fences here: all cross-wg data moves via sc1 (agent-scope) accesses,
// so L2 retains weights/K/V across all 252 phases (was: buffer_inv per phase).
__device__ __forceinline__ void gbar(unsigned* bar, int ep) {
    __syncthreads();                        // drains vmcnt per wave before s_barrier
    if (threadIdx.x == 0) {
        asm volatile("s_waitcnt vmcnt(0)" ::: "memory");
        unsigned* c = bar + ep * 32;
        __hip_atomic_fetch_add(c, 1u, __ATOMIC_RELAXED, __HIP_MEMORY_SCOPE_AGENT);
        while (__hip_atomic_load(c, __ATOMIC_RELAXED, __HIP_MEMORY_SCOPE_AGENT) < (unsigned)GRID_REC) {
            __builtin_amdgcn_s_sleep(1);
        }
    }
    __syncthreads();
}

// src layout [512][32] -> X[b*513 + k]; coherent (sc1) 8B loads
__device__ __forceinline__ void stageX(float* X, const float* __restrict__ src) {
    unsigned long long* s = (unsigned long long*)src;
    unsigned long long v[32];
    #pragma unroll
    for (int w = 0; w < 32; ++w)
        v[w] = ldA64(s + w * 256 + threadIdx.x);
    #pragma unroll
    for (int w = 0; w < 32; ++w) {
        int i = w * 256 + threadIdx.x;
        union { unsigned long long u; float f[2]; } c; c.u = v[w];
        int e = i * 2;
        int j = e >> 5, b0 = e & 31;
        X[(b0 + 0) * 513 + j] = c.f[0];
        X[(b0 + 1) * 513 + j] = c.f[1];
    }
}

__device__ __forceinline__ float dot128(const float* __restrict__ w, const float* x) {
    float acc = 0.f;
    #pragma unroll 8
    for (int k = 0; k < 128; k += 4) {
        float4 a = *(const float4*)(w + k);
        acc += a.x * x[k] + a.y * x[k+1] + a.z * x[k+2] + a.w * x[k+3];
    }
    return acc;
}

__device__ __forceinline__ void dot128x3(const float* __restrict__ w0,
        const float* __restrict__ w1, const float* __restrict__ w2,
        const float* x, float* out3) {
    float a0 = 0.f, a1 = 0.f, a2 = 0.f;
    #pragma unroll 8
    for (int k = 0; k < 128; k += 4) {
        float x0 = x[k], x1 = x[k+1], x2 = x[k+2], x3 = x[k+3];
        float4 wa = *(const float4*)(w0 + k);
        float4 wb = *(const float4*)(w1 + k);
        float4 wc = *(const float4*)(w2 + k);
        a0 += wa.x*x0 + wa.y*x1 + wa.z*x2 + wa.w*x3;
        a1 += wb.x*x0 + wb.y*x1 + wb.z*x2 + wb.w*x3;
        a2 += wc.x*x0 + wc.y*x1 + wc.z*x2 + wc.w*x3;
    }
    out3[0] = a0; out3[1] = a1; out3[2] = a2;
}

__global__ __launch_bounds__(256, 1) void k_rec(
        const float* __restrict__ kht, const float* __restrict__ vh,
        const float* __restrict__ gie, const int* __restrict__ maskp,
        const float* __restrict__ wq,  const float* __restrict__ bq,
        const float* __restrict__ wo,  const float* __restrict__ bo,
        const float* __restrict__ wih0, const float* __restrict__ whh0, const float* __restrict__ bhh0,
        const float* __restrict__ wih1, const float* __restrict__ bih1,
        const float* __restrict__ whh1, const float* __restrict__ bhh1,
        float* __restrict__ ctxA, float* __restrict__ ctxo,
        float* __restrict__ h0c, float* __restrict__ h0n,
        float* __restrict__ h1c, float* __restrict__ h1r,
        unsigned short* __restrict__ comb, unsigned* bar) {
    __shared__ float X[32 * 513];
    __shared__ float sc[S];
    __shared__ float qv[64];
    __shared__ float pq[64 * 4];
    __shared__ float cp[4 * 64];
    __shared__ float pr[4 * 32 * 6];
    __shared__ float red[8];

    const int wg = blockIdx.x, tid = threadIdx.x;
    const int ab = wg >> 3, ah = wg & 7;          // phase A identity (b, head)
    const int j0 = wg * 2;                        // B/C/D: rows j0, j0+1
    const int j2 = tid >> 7;
    const int pp = (tid >> 5) & 3;
    const int bb = tid & 31;
    const int jme = j0 + j2;
    const int wid = tid >> 6;
    const bool fin = tid < 64;
    const int fj2 = tid >> 5, fb = tid & 31;      // valid when fin
    const bool apad = (maskp[ab * S + tid] == 0);
    int ep = 0;

    for (int t = 0; t < TS; ++t) {
        // double-buffered recurrent state (race-free across the phase window)
        float* h0rd = h0c + (((t & 1) ^ 1) << 14);
        float* h0wr = h0c + ((t & 1) << 14);
        float* h1rd = h1c + (((t & 1) ^ 1) << 14);
        float* h1wr = h1c + ((t & 1) << 14);

        // ====== Phase A: q + attention for (ab, ah) ======
        {
            union { unsigned long long u; float f[2]; } c;
            c.u = ldA64((unsigned long long*)(h1r + ab * H) + tid);
            X[tid * 2] = c.f[0]; X[tid * 2 + 1] = c.f[1];
        }
        __syncthreads();
        {   // q partials: f = tid>>2, p = tid&3
            int f = tid >> 2, p = tid & 3;
            const float* wr = wq + (size_t)(ah * 64 + f) * H + p * 128;
            pq[f * 4 + p] = dot128(wr, X + p * 128);
        }
        __syncthreads();
        if (tid < 64)
            qv[tid] = clipf(pq[tid*4] + pq[tid*4+1] + pq[tid*4+2] + pq[tid*4+3]
                            + bq[ah * 64 + tid], -100.f, 100.f);
        __syncthreads();
        {   // scores: thread = s
            const float* kr = kht + ((size_t)ab * H + ah * 64) * S + tid;
            float acc = 0.f;
            #pragma unroll 8
            for (int d = 0; d < 64; ++d) acc += qv[d] * kr[(size_t)d * S];
            sc[tid] = apad ? -10000.f : acc * 0.125f;
        }
        __syncthreads();
        {   // softmax over 256
            float v = sc[tid];
            float m = v;
            for (int o = 32; o >= 1; o >>= 1) m = fmaxf(m, __shfl_xor(m, o, 64));
            if ((tid & 63) == 0) red[wid] = m;
            __syncthreads();
            m = fmaxf(fmaxf(red[0], red[1]), fmaxf(red[2], red[3]));
            float e = __expf(v - m);
            float s = e;
            for (int o = 32; o >= 1; o >>= 1) s += __shfl_xor(s, o, 64);
            if ((tid & 63) == 0) red[4 + wid] = s;
            __syncthreads();
            float inv = 1.f / (red[4] + red[5] + red[6] + red[7]);
            sc[tid] = e * inv;
        }
        __syncthreads();
        {   // ctx: d = tid&63, chunk c = tid>>6
            int d = tid & 63, c = tid >> 6;
            const float* vr = vh + ((size_t)ab * S + c * 64) * H + ah * 64 + d;
            float acc = 0.f;
            #pragma unroll 4
            for (int s2 = 0; s2 < 64; ++s2) acc += sc[c * 64 + s2] * vr[(size_t)s2 * H];
            cp[c * 64 + d] = acc;
        }
        __syncthreads();
        if (tid < 64)
            stA(&ctxA[(ah * 64 + tid) * 32 + ab],
                cp[tid] + cp[64 + tid] + cp[128 + tid] + cp[192 + tid]);
        gbar(bar, ep++);

        // ====== Phase B: ctxo = clip(ctx @ wo.T + bo) ======
        stageX(X, ctxA);
        __syncthreads();
        {
            const float* wr = wo + (size_t)jme * H + pp * 128;
            float acc = dot128(wr, X + bb * 513 + pp * 128);
            acc += __shfl_xor(acc, 32, 64);
            if ((tid & 63) < 32) pr[wid * 32 + bb] = acc;
        }
        __syncthreads();
        if (fin) {
            int j = j0 + fj2;
            float v = pr[(fj2 * 2) * 32 + fb] + pr[(fj2 * 2 + 1) * 32 + fb] + bo[j];
            v = clipf(v, -100.f, 100.f);
            stA(&ctxo[j * 32 + fb], v);
            comb[((size_t)(t * 32 + fb)) * 1024 + 512 + j] = f2bf(v);
        }
        gbar(bar, ep++);

        // ====== Phase C: GRU0 ======
        stageX(X, ctxo);
        __syncthreads();
        float gi3[3], gh3[3];
        dot128x3(wih0 + (size_t)jme * 1024 + 512 + pp * 128,
                 wih0 + (size_t)(jme + 512) * 1024 + 512 + pp * 128,
                 wih0 + (size_t)(jme + 1024) * 1024 + 512 + pp * 128,
                 X + bb * 513 + pp * 128, gi3);
        __syncthreads();
        stageX(X, h0rd);
        __syncthreads();
        dot128x3(whh0 + (size_t)jme * H + pp * 128,
                 whh0 + (size_t)(jme + 512) * H + pp * 128,
                 whh0 + (size_t)(jme + 1024) * H + pp * 128,
                 X + bb * 513 + pp * 128, gh3);
        {
            #pragma unroll
            for (int g = 0; g < 3; ++g) {
                gi3[g] += __shfl_xor(gi3[g], 32, 64);
                gh3[g] += __shfl_xor(gh3[g], 32, 64);
            }
            if ((tid & 63) < 32) {
                float* p = pr + (wid * 32 + bb) * 6;
                p[0] = gi3[0]; p[1] = gi3[1]; p[2] = gi3[2];
                p[3] = gh3[0]; p[4] = gh3[1]; p[5] = gh3[2];
            }
        }
        __syncthreads();
        if (fin) {
            int j = j0 + fj2;
            const float* pa = pr + ((fj2 * 2) * 32 + fb) * 6;
            const float* pb = pr + ((fj2 * 2 + 1) * 32 + fb) * 6;
            float gir = pa[0] + pb[0] + gie[((size_t)t * G3 + j) * 32 + fb];
            float giz = pa[1] + pb[1] + gie[((size_t)t * G3 + 512 + j) * 32 + fb];
            float gin = pa[2] + pb[2] + gie[((size_t)t * G3 + 1024 + j) * 32 + fb];
            float ghr = pa[3] + pb[3] + bhh0[j];
            float ghz = pa[4] + pb[4] + bhh0[512 + j];
            float ghn = pa[5] + pb[5] + bhh0[1024 + j];
            float r_ = sigf(gir + ghr);
            float z_ = sigf(giz + ghz);
            float n_ = tanhf(gin + r_ * ghn);
            float h0old = X[fb * 513 + j];              // X holds h0rd
            float hn = (1.f - z_) * n_ + z_ * h0old;
            stA(&h0n[j * 32 + fb], hn);
            stA(&h0wr[j * 32 + fb], clipf(hn, -10.f, 10.f));
        }
        gbar(bar, ep++);

        // ====== Phase D: GRU1 ======
        stageX(X, h0n);
        __syncthreads();
        dot128x3(wih1 + (size_t)jme * H + pp * 128,
                 wih1 + (size_t)(jme + 512) * H + pp * 128,
                 wih1 + (size_t)(jme + 1024) * H + pp * 128,
                 X + bb * 513 + pp * 128, gi3);
        __syncthreads();
        stageX(X, h1rd);
        __syncthreads();
        dot128x3(whh1 + (size_t)jme * H + pp * 128,
                 whh1 + (size_t)(jme + 512) * H + pp * 128,
                 whh1 + (size_t)(jme + 1024) * H + pp * 128,
                 X + bb * 513 + pp * 128, gh3);
        {
            #pragma unroll
            for (int g = 0; g < 3; ++g) {
                gi3[g] += __shfl_xor(gi3[g], 32, 64);
                gh3[g] += __shfl_xor(gh3[g], 32, 64);
            }
            if ((tid & 63) < 32) {
                float* p = pr + (wid * 32 + bb) * 6;
                p[0] = gi3[0]; p[1] = gi3[1]; p[2] = gi3[2];
                p[3] = gh3[0]; p[4] = gh3[1]; p[5] = gh3[2];
            }
        }
        __syncthreads();
        if (fin) {
            int j = j0 + fj2;
            const float* pa = pr + ((fj2 * 2) * 32 + fb) * 6;
            const float* pb = pr + ((fj2 * 2 + 1) * 32 + fb) * 6;
            float gir = pa[0] + pb[0] + bih1[j];
            float giz = pa[1] + pb[1] + bih1[512 + j];
            float gin = pa[2] + pb[2] + bih1[1024 + j];
            float ghr = pa[3] + pb[3] + bhh1[j];
            float ghz = pa[4] + pb[4] + bhh1[512 + j];
            float ghn = pa[5] + pb[5] + bhh1[1024 + j];
            float r_ = sigf(gir + ghr);
            float z_ = sigf(giz + ghz);
            float n_ = tanhf(gin + r_ * ghn);
            float h1old = X[fb * 513 + j];              // X holds h1rd
            float hn = (1.f - z_) * n_ + z_ * h1old;
            float hc = clipf(hn, -10.f, 10.f);
            stA(&h1wr[j * 32 + fb], hc);
            stA(&h1r[fb * H + j], hc);
            comb[((size_t)(t * 32 + fb)) * 1024 + j] = f2bf(hn);
        }
        gbar(bar, ep++);
    }
}

// ---------------- MFMA bf16 GEMMs for output MLP ----------------
__device__ __forceinline__ void mfma_tile64(const unsigned short* A, int lda,
        const unsigned short* Bm, int ldb, int K, int arow0, int Mmax, f32x4 acc[4][4]) {
    int lane = threadIdx.x & 63;
    int m16 = lane & 15, q = lane >> 4;
    const unsigned short* ar[4];
    const unsigned short* br[4];
    #pragma unroll
    for (int mi = 0; mi < 4; ++mi) {
        int row = arow0 + mi * 16 + m16; if (row >= Mmax) row = Mmax - 1;
        ar[mi] = A + (size_t)row * lda + q * 8;
    }
    #pragma unroll
    for (int ni = 0; ni < 4; ++ni) br[ni] = Bm + (size_t)(ni * 16 + m16) * ldb + q * 8;
    for (int k = 0; k < K; k += 32) {
        bf16x8 af[4], bfr[4];
        #pragma unroll
        for (int mi = 0; mi < 4; ++mi) af[mi] = *(const bf16x8*)(ar[mi] + k);
        #pragma unroll
        for (int ni = 0; ni < 4; ++ni) bfr[ni] = *(const bf16x8*)(br[ni] + k);
        #pragma unroll
        for (int mi = 0; mi < 4; ++mi)
            #pragma unroll
            for (int ni = 0; ni < 4; ++ni)
                acc[mi][ni] = __builtin_amdgcn_mfma_f32_16x16x32_bf16(af[mi], bfr[ni], acc[mi][ni], 0, 0, 0);
    }
}

__global__ __launch_bounds__(256) void k_g1(const unsigned short* __restrict__ comb,
        const unsigned short* __restrict__ w1b, const float* __restrict__ b1,
        unsigned short* __restrict__ h1out) {
    int wave = threadIdx.x >> 6, lane = threadIdx.x & 63;
    int wm = wave >> 1, wn = wave & 1;
    int m0 = blockIdx.y * 128 + wm * 64;
    int n0 = blockIdx.x * 128 + wn * 64;
    f32x4 acc[4][4];
    #pragma unroll
    for (int i = 0; i < 4; ++i)
        #pragma unroll
        for (int j = 0; j < 4; ++j) acc[i][j] = (f32x4){0.f, 0.f, 0.f, 0.f};
    mfma_tile64(comb, 1024, w1b + (size_t)n0 * 1024, 1024, 1024, m0, NR, acc);
    int q = lane >> 4, m16 = lane & 15;
    #pragma unroll
    for (int mi = 0; mi < 4; ++mi)
        #pragma unroll
        for (int ni = 0; ni < 4; ++ni) {
            int n = n0 + ni * 16 + m16;
            float bias = b1[n];
            #pragma unroll
            for (int rg = 0; rg < 4; ++rg) {
                int row = m0 + mi * 16 + q * 4 + rg;
                if (row < NR) {
                    float v = fmaxf(acc[mi][ni][rg] + bias, 0.f);
                    h1out[(size_t)row * 512 + n] = f2bf(v);
                }
            }
        }
}

__global__ __launch_bounds__(256) void k_g2(const unsigned short* __restrict__ h1b,
        const unsigned short* __restrict__ w2b, const float* __restrict__ b2,
        float* __restrict__ out) {
    int wave = threadIdx.x >> 6, lane = threadIdx.x & 63;
    int wm = wave >> 1, wn = wave & 1;
    int m0 = blockIdx.y * 128 + wm * 64;
    int n0 = blockIdx.x * 128 + wn * 64;
    f32x4 acc[4][4];
    #pragma unroll
    for (int i = 0; i < 4; ++i)
        #pragma unroll
        for (int j = 0; j < 4; ++j) acc[i][j] = (f32x4){0.f, 0.f, 0.f, 0.f};
    mfma_tile64(h1b, 512, w2b + (size_t)n0 * 512, 512, 512, m0, NR, acc);
    int q = lane >> 4, m16 = lane & 15;
    #pragma unroll
    for (int mi = 0; mi < 4; ++mi)
        #pragma unroll
        for (int ni = 0; ni < 4; ++ni) {
            int n = n0 + ni * 16 + m16;
            float bias = b2[n];
            #pragma unroll
            for (int rg = 0; rg < 4; ++rg) {
                int row = m0 + mi * 16 + q * 4 + rg;
                if (row < NR) {
                    int t = row >> 5, b = row & 31;
                    float v = clipf(acc[mi][ni][rg] + bias, -100.f, 100.f);
                    out[(size_t)b * T * V + (size_t)(t + 1) * V + n] = v;
                }
            }
        }
}

// ---------------- launch ----------------

extern "C" void kernel_launch(void* const* d_in, const int* in_sizes, int n_in,
                              void* d_out, int out_size, void* d_ws, size_t ws_size,
                              hipStream_t stream) {
    const int*   tgt  = (const int*)d_in[0];
    const float* enc  = (const float*)d_in[1];
    const float* dec  = (const float*)d_in[2];
    const int*   mask = (const int*)d_in[3];
    const float* embt = (const float*)d_in[4];
    const float* wep  = (const float*)d_in[5];  const float* bep = (const float*)d_in[6];
    const float* wq   = (const float*)d_in[7];  const float* bq  = (const float*)d_in[8];
    const float* wk   = (const float*)d_in[9];  const float* bk  = (const float*)d_in[10];
    const float* wv   = (const float*)d_in[11]; const float* bv  = (const float*)d_in[12];
    const float* wo   = (const float*)d_in[13]; const float* bo  = (const float*)d_in[14];
    const float* wih0 = (const float*)d_in[15]; const float* whh0 = (const float*)d_in[16];
    const float* bih0 = (const float*)d_in[17]; const float* bhh0 = (const float*)d_in[18];
    const float* wih1 = (const float*)d_in[19]; const float* whh1 = (const float*)d_in[20];
    const float* bih1 = (const float*)d_in[21]; const float* bhh1 = (const float*)d_in[22];
    const float* wo1  = (const float*)d_in[23]; const float* bo1 = (const float*)d_in[24];
    const float* wo2  = (const float*)d_in[25]; const float* bo2 = (const float*)d_in[26];
    float* out = (float*)d_out;
    char* ws = (char*)d_ws;

    float* kht           = (float*)(ws + 0);
    float* vh            = (float*)(ws + 16777216);
    float* gie           = (float*)(ws + 33554432);
    unsigned short* comb = (unsigned short*)(ws + 45940736);
    unsigned short* h1b  = (unsigned short*)(ws + 50069504);
    unsigned short* w1b  = (unsigned short*)(ws + 52133888);
    unsigned short* w2b  = (unsigned short*)(ws + 53182464);
    float* ctxA          = (float*)(ws + 85950464);
    float* ctxo          = (float*)(ws + 86016000);
    float* h0n           = (float*)(ws + 86081536);
    float* h0c           = (float*)(ws + 86147072);   // 2 x 64KB (double-buffered)
    float* h1c           = (float*)(ws + 86278144);   // 2 x 64KB (double-buffered)
    float* h1r           = (float*)(ws + 86409216);
    unsigned* bar        = (unsigned*)(ws + 86474752);   // 32 KB

    hipMemsetAsync(bar, 0, 256 * 32 * sizeof(unsigned), stream);
    hipLaunchKernelGGL(k_zero_t0, dim3(1000), dim3(256), 0, stream, out);
    // init writes the parity-1 buffers (read at t=0)
    hipLaunchKernelGGL(k_init_h, dim3(64), dim3(256), 0, stream, dec,
                       h0c + 16384, h1c + 16384, h1r);
    hipLaunchKernelGGL(k_kv, dim3(B * S), dim3(256), 0, stream, enc, wk, bk, wv, bv, kht, vh);
    hipLaunchKernelGGL(k_gie, dim3(NR), dim3(256), 0, stream, tgt, embt, wep, bep, wih0, bih0, gie);
    hipLaunchKernelGGL(k_cvt, dim3(4096), dim3(256), 0, stream, wo1, wo2, w1b, w2b);
    hipLaunchKernelGGL(k_rec, dim3(GRID_REC), dim3(256), 0, stream,
                       kht, vh, gie, mask, wq, bq, wo, bo,
                       wih0, whh0, bhh0, wih1, bih1, whh1, bhh1,
                       ctxA, ctxo, h0c, h0n, h1c, h1r, comb, bar);
    hipLaunchKernelGGL(k_g1, dim3(4, 16), dim3(256), 0, stream, comb, w1b, bo1, h1b);
    hipLaunchKernelGGL(k_g2, dim3(250, 16), dim3(256), 0, stream, h1b, w2b, bo2, out);
}

// Round 2
// 5884.332 us; speedup vs baseline: 1.8269x; 1.7476x over previous
//
#include <hip/hip_runtime.h>
#include <hip/hip_bf16.h>
#include <math.h>

#define B 32
#define T 64
#define S 256
#define H 512
#define E 256
#define V 32000
#define NH 8
#define HD 64
#define TS 63          // steps (T-1)
#define NR 2016        // TS*B rows
#define G3 1536        // 3*H

typedef short bf16x8 __attribute__((ext_vector_type(8)));
typedef float f32x4 __attribute__((ext_vector_type(4)));

__device__ __forceinline__ unsigned short f2bf(float f) {
    union { float f; unsigned u; } v; v.f = f;
    unsigned r = v.u + 0x7FFF + ((v.u >> 16) & 1);   // RNE
    return (unsigned short)(r >> 16);
}
__device__ __forceinline__ float clipf(float v, float lo, float hi) {
    return fminf(hi, fmaxf(lo, v));
}
__device__ __forceinline__ float sigf(float x) { return 1.0f / (1.0f + __expf(-x)); }

// agent-scope (coherence-point) accessors for cross-WG data inside k_rec
__device__ __forceinline__ void stA(float* p, float v) {
    __hip_atomic_store(p, v, __ATOMIC_RELAXED, __HIP_MEMORY_SCOPE_AGENT);
}
__device__ __forceinline__ unsigned long long ldA64(const void* p) {
    return __hip_atomic_load((const unsigned long long*)p, __ATOMIC_RELAXED, __HIP_MEMORY_SCOPE_AGENT);
}

// padded LDS segment layout: 128-float segments at pitch 132 (bank-spread partials)
#define XIDX(k) ((((k) >> 7) * 132) + ((k) & 127))
#define BLP 528   // per-batch pitch = 4*132

// ---------------- prolog kernels ----------------

__global__ void k_zero_t0(float* out) {
    int idx = blockIdx.x * 256 + threadIdx.x;        // over B*V/4
    int n = B * V / 4;
    if (idx < n) {
        int b = idx / (V / 4);
        int v4 = idx % (V / 4);
        float4* p = (float4*)(out + (size_t)b * T * V) + v4;
        *p = make_float4(0.f, 0.f, 0.f, 0.f);
    }
}

// writes initial state into parity-1 buffers of h0n / h1s ([2][B][512] row-major)
__global__ void k_init_h(const float* dec, float* h0n, float* h1s) {
    int i = blockIdx.x * 256 + threadIdx.x;
    if (i < B * H) {
        float v = clipf(dec[i], -10.f, 10.f);
        h0n[16384 + i] = v;
        h1s[16384 + i] = v;
    }
}

// K/V projections: 8 enc rows per WG so wk/wv stream 16x less from L2
__global__ __launch_bounds__(256) void k_kv(const float* __restrict__ enc,
        const float* __restrict__ wk, const float* __restrict__ bk,
        const float* __restrict__ wv, const float* __restrict__ bv,
        float* __restrict__ kht, float* __restrict__ vh) {
    __shared__ float x[8][512];
    int r0 = blockIdx.x * 8;
    for (int idx = threadIdx.x; idx < 4096; idx += 256) {
        int rr = idx >> 9, k = idx & 511;
        x[rr][k] = enc[(size_t)(r0 + rr) * 512 + k];
    }
    __syncthreads();
    int b = r0 >> 8, s0 = r0 & 255;
    for (int ii = 0; ii < 2; ++ii) {
        int i = threadIdx.x + ii * 256;
        const float* wkr = wk + (size_t)i * 512;
        const float* wvr = wv + (size_t)i * 512;
        float aK[8], aV[8];
        float bk0 = bk[i], bv0 = bv[i];
        #pragma unroll
        for (int rr = 0; rr < 8; ++rr) { aK[rr] = bk0; aV[rr] = bv0; }
        for (int k = 0; k < 512; k += 4) {
            float4 a = *(const float4*)(wkr + k);
            float4 c = *(const float4*)(wvr + k);
            #pragma unroll
            for (int rr = 0; rr < 8; ++rr) {
                float4 xv = *(const float4*)(&x[rr][k]);
                aK[rr] += a.x*xv.x + a.y*xv.y + a.z*xv.z + a.w*xv.w;
                aV[rr] += c.x*xv.x + c.y*xv.y + c.z*xv.z + c.w*xv.w;
            }
        }
        #pragma unroll
        for (int rr = 0; rr < 8; ++rr) {
            kht[((size_t)b * 512 + i) * 256 + s0 + rr] = clipf(aK[rr], -100.f, 100.f);
            vh[((size_t)b * 256 + s0 + rr) * 512 + i] = aV[rr];
        }
    }
}

// gie[(t*32+b)*1536 + j] = b_ih0[j] + emb(t,b) . w_ih0[j, 0:512]; 8 rows per WG
__global__ __launch_bounds__(256) void k_gie(const int* __restrict__ tgt,
        const float* __restrict__ embt, const float* __restrict__ wep,
        const float* __restrict__ bep, const float* __restrict__ wih0,
        const float* __restrict__ bih0, float* __restrict__ gie) {
    __shared__ float er[8][256];
    __shared__ float xf[8][512];
    int r0 = blockIdx.x * 8;
    for (int idx = threadIdx.x; idx < 2048; idx += 256) {
        int rr = idx >> 8, k = idx & 255;
        int rw = r0 + rr; int tt = rw >> 5, bb = rw & 31;
        er[rr][k] = embt[(size_t)tgt[bb * T + tt] * 256 + k];
    }
    __syncthreads();
    for (int ii = 0; ii < 2; ++ii) {
        int i = threadIdx.x + ii * 256;
        const float* wr = wep + (size_t)i * 256;
        float acc[8];
        float b0 = bep[i];
        #pragma unroll
        for (int rr = 0; rr < 8; ++rr) acc[rr] = b0;
        for (int k = 0; k < 256; k += 4) {
            float4 w4 = *(const float4*)(wr + k);
            #pragma unroll
            for (int rr = 0; rr < 8; ++rr) {
                float4 xv = *(const float4*)(&er[rr][k]);
                acc[rr] += w4.x*xv.x + w4.y*xv.y + w4.z*xv.z + w4.w*xv.w;
            }
        }
        #pragma unroll
        for (int rr = 0; rr < 8; ++rr) xf[rr][i] = acc[rr];
    }
    __syncthreads();
    for (int jj = 0; jj < 6; ++jj) {
        int j = threadIdx.x + jj * 256;
        const float* wr = wih0 + (size_t)j * 1024;   // emb part = cols 0..511
        float acc[8];
        float b0 = bih0[j];
        #pragma unroll
        for (int rr = 0; rr < 8; ++rr) acc[rr] = b0;
        for (int k = 0; k < 512; k += 4) {
            float4 w4 = *(const float4*)(wr + k);
            #pragma unroll
            for (int rr = 0; rr < 8; ++rr) {
                float4 xv = *(const float4*)(&xf[rr][k]);
                acc[rr] += w4.x*xv.x + w4.y*xv.y + w4.z*xv.z + w4.w*xv.w;
            }
        }
        #pragma unroll
        for (int rr = 0; rr < 8; ++rr) gie[(size_t)(r0 + rr) * 1536 + j] = acc[rr];
    }
}

__global__ void k_cvt(const float* __restrict__ wo1, const float* __restrict__ wo2,
                      unsigned short* __restrict__ w1b, unsigned short* __restrict__ w2b) {
    size_t idx = (size_t)blockIdx.x * 256 + threadIdx.x;
    size_t stride = (size_t)gridDim.x * 256;
    size_t n1 = (size_t)H * 2 * H;
    size_t n2 = (size_t)V * H;
    for (size_t i = idx; i < n1; i += stride) w1b[i] = f2bf(wo1[i]);
    for (size_t i = idx; i < n2; i += stride) w2b[i] = f2bf(wo2[i]);
}

// ---------------- persistent recurrence kernel ----------------
// 8 independent groups x 32 WGs; group g owns batches [4g, 4g+4).
// Barriers are per-group (32-way), monotone counter.

__device__ __forceinline__ void gbar(unsigned* c, unsigned target) {
    __syncthreads();                 // drains vmcnt per wave before s_barrier
    if (threadIdx.x == 0) {
        asm volatile("s_waitcnt vmcnt(0)" ::: "memory");
        __hip_atomic_fetch_add(c, 1u, __ATOMIC_RELAXED, __HIP_MEMORY_SCOPE_AGENT);
        while (__hip_atomic_load(c, __ATOMIC_RELAXED, __HIP_MEMORY_SCOPE_AGENT) < target) {
            __builtin_amdgcn_s_sleep(1);
        }
    }
    __syncthreads();
}

// stage 4 batch-vectors (2048 floats) from global [4*512] into padded LDS [4][4][132]
__device__ __forceinline__ void stage4(float* dst, const float* src, bool doclip) {
    const unsigned long long* s = (const unsigned long long*)src;
    #pragma unroll
    for (int i = 0; i < 4; ++i) {
        int w = threadIdx.x + i * 256;        // 0..1023
        union { unsigned long long u; float f[2]; } c;
        c.u = ldA64(s + w);
        int bl = w >> 8;
        int k = (w & 255) * 2;
        float a = c.f[0], b2 = c.f[1];
        if (doclip) { a = clipf(a, -10.f, 10.f); b2 = clipf(b2, -10.f, 10.f); }
        int base = bl * BLP + XIDX(k);
        dst[base] = a; dst[base + 1] = b2;
    }
}

__device__ __forceinline__ float dot128(const float* __restrict__ w, const float* x) {
    float acc = 0.f;
    #pragma unroll 8
    for (int k = 0; k < 128; k += 4) {
        float4 a = *(const float4*)(w + k);
        acc += a.x * x[k] + a.y * x[k+1] + a.z * x[k+2] + a.w * x[k+3];
    }
    return acc;
}

__global__ __launch_bounds__(256, 1) void k_rec(
        const float* __restrict__ kht, const float* __restrict__ vh,
        const float* __restrict__ gie, const int* __restrict__ maskp,
        const float* __restrict__ wq,  const float* __restrict__ bq,
        const float* __restrict__ wo,  const float* __restrict__ bo,
        const float* __restrict__ wih0, const float* __restrict__ whh0, const float* __restrict__ bhh0,
        const float* __restrict__ wih1, const float* __restrict__ bih1,
        const float* __restrict__ whh1, const float* __restrict__ bhh1,
        float* __restrict__ ctx, float* __restrict__ ctxo,
        float* __restrict__ h0n, float* __restrict__ h1s,
        unsigned short* __restrict__ comb, unsigned* bar) {
    __shared__ float SA[4 * BLP];
    __shared__ float SB[4 * BLP];
    __shared__ float pq[256];
    __shared__ float qv[64];
    __shared__ float sc[256];
    __shared__ float cp[256];
    __shared__ float red[8];

    const int tid = threadIdx.x;
    const int wgid = blockIdx.x;
    const int grp = wgid >> 5;            // 0..7
    const int w = wgid & 31;              // 0..31 within group
    const int bg0 = grp * 4;              // first batch of group
    const int ab = bg0 + (w >> 3);        // phase A: batch
    const int ah = w & 7;                 // phase A: head
    const int jb = w * 16;                // row slab base for B/C/D
    const int bl = tid >> 6;              // wave index = local batch for B/C/D
    const int lane = tid & 63;
    const int r = lane & 15;
    const int p4 = lane >> 4;             // partial index 0..3
    const int bg = bg0 + bl;              // global batch for B/C/D
    const bool fin = (lane < 16);
    const int wid = tid >> 6;
    const bool apad = (maskp[ab * S + tid] == 0);
    unsigned* barp = bar + grp * 64;      // 256B-padded per-group counter
    unsigned bcount = 0;

    for (int t = 0; t < TS; ++t) {
        const int par = t & 1;
        const float* h1rd = h1s + (par ^ 1) * 16384;
        float* h1wr = h1s + par * 16384;
        const float* h0rd = h0n + (par ^ 1) * 16384;
        float* h0wr = h0n + par * 16384;

        // ====== Phase A: attention for (ab, ah) ======
        {
            union { unsigned long long u; float f[2]; } c;
            c.u = ldA64((const unsigned long long*)(h1rd + ab * 512) + tid);
            int k2 = tid * 2;
            SA[XIDX(k2)]     = clipf(c.f[0], -10.f, 10.f);
            SA[XIDX(k2) + 1] = clipf(c.f[1], -10.f, 10.f);
        }
        __syncthreads();
        {   // q partials: f = tid>>2, p = tid&3
            int f = tid >> 2, p = tid & 3;
            pq[f * 4 + p] = dot128(wq + (size_t)(ah * 64 + f) * 512 + p * 128, SA + p * 132);
        }
        __syncthreads();
        if (tid < 64)
            qv[tid] = clipf(pq[tid*4] + pq[tid*4+1] + pq[tid*4+2] + pq[tid*4+3]
                            + bq[ah * 64 + tid], -100.f, 100.f);
        __syncthreads();
        {   // scores: thread = s
            const float* kr = kht + ((size_t)ab * 512 + ah * 64) * 256 + tid;
            float acc = 0.f;
            #pragma unroll 8
            for (int d = 0; d < 64; ++d) acc += qv[d] * kr[(size_t)d * 256];
            sc[tid] = apad ? -10000.f : acc * 0.125f;
        }
        __syncthreads();
        {   // softmax over 256
            float v = sc[tid];
            float m = v;
            for (int o = 32; o >= 1; o >>= 1) m = fmaxf(m, __shfl_xor(m, o, 64));
            if ((tid & 63) == 0) red[wid] = m;
            __syncthreads();
            m = fmaxf(fmaxf(red[0], red[1]), fmaxf(red[2], red[3]));
            float e = __expf(v - m);
            float s = e;
            for (int o = 32; o >= 1; o >>= 1) s += __shfl_xor(s, o, 64);
            if ((tid & 63) == 0) red[4 + wid] = s;
            __syncthreads();
            float inv = 1.f / (red[4] + red[5] + red[6] + red[7]);
            sc[tid] = e * inv;
        }
        __syncthreads();
        {   // ctx partials: d = tid&63, chunk c = tid>>6
            const float* vr = vh + ((size_t)ab * 256 + (tid >> 6) * 64) * 512 + ah * 64 + (tid & 63);
            float acc = 0.f;
            #pragma unroll 4
            for (int s2 = 0; s2 < 64; ++s2) acc += sc[(tid >> 6) * 64 + s2] * vr[(size_t)s2 * 512];
            cp[tid] = acc;
        }
        __syncthreads();
        if (tid < 64)
            stA(&ctx[ab * 512 + ah * 64 + tid],
                cp[tid] + cp[64 + tid] + cp[128 + tid] + cp[192 + tid]);
        gbar(barp, (++bcount) * 32);

        // ====== Phase B: ctxo rows [jb, jb+16) for the group's 4 batches ======
        stage4(SA, ctx + bg0 * 512, false);
        __syncthreads();
        {
            float a = dot128(wo + (size_t)(jb + r) * 512 + p4 * 128, SA + bl * BLP + p4 * 132);
            a += __shfl_xor(a, 16, 64);
            a += __shfl_xor(a, 32, 64);
            if (fin) {
                int j = jb + r;
                float v = clipf(a + bo[j], -100.f, 100.f);
                stA(&ctxo[bg * 512 + j], v);
                comb[(size_t)(t * 32 + bg) * 1024 + 512 + j] = f2bf(v);
            }
        }
        gbar(barp, (++bcount) * 32);

        // ====== Phase C: GRU0 ======
        stage4(SA, ctxo + bg0 * 512, false);
        stage4(SB, h0rd + bg0 * 512, true);
        __syncthreads();
        float gi3[3], gh3[3];
        #pragma unroll
        for (int g3 = 0; g3 < 3; ++g3) {
            int row = g3 * 512 + jb + r;
            float gi = dot128(wih0 + (size_t)row * 1024 + 512 + p4 * 128, SA + bl * BLP + p4 * 132);
            float gh = dot128(whh0 + (size_t)row * 512 + p4 * 128, SB + bl * BLP + p4 * 132);
            gi += __shfl_xor(gi, 16, 64); gi += __shfl_xor(gi, 32, 64);
            gh += __shfl_xor(gh, 16, 64); gh += __shfl_xor(gh, 32, 64);
            gi3[g3] = gi; gh3[g3] = gh;
        }
        if (fin) {
            int j = jb + r;
            const float* gp = gie + (size_t)(t * 32 + bg) * 1536;
            float gir = gi3[0] + gp[j];
            float giz = gi3[1] + gp[512 + j];
            float gin = gi3[2] + gp[1024 + j];
            float ghr = gh3[0] + bhh0[j];
            float ghz = gh3[1] + bhh0[512 + j];
            float ghn = gh3[2] + bhh0[1024 + j];
            float r_ = sigf(gir + ghr);
            float z_ = sigf(giz + ghz);
            float n_ = tanhf(gin + r_ * ghn);
            float h0old = SB[bl * BLP + XIDX(j)];        // clipped prev h0
            float hn = (1.f - z_) * n_ + z_ * h0old;
            stA(&h0wr[bg * 512 + j], hn);                // preclip; clip on read
        }
        gbar(barp, (++bcount) * 32);

        // ====== Phase D: GRU1 ======
        stage4(SA, h0wr + bg0 * 512, false);             // h0 preclip (GRU1 input)
        stage4(SB, h1rd + bg0 * 512, true);              // h1 prev clipped
        __syncthreads();
        #pragma unroll
        for (int g3 = 0; g3 < 3; ++g3) {
            int row = g3 * 512 + jb + r;
            float gi = dot128(wih1 + (size_t)row * 512 + p4 * 128, SA + bl * BLP + p4 * 132);
            float gh = dot128(whh1 + (size_t)row * 512 + p4 * 128, SB + bl * BLP + p4 * 132);
            gi += __shfl_xor(gi, 16, 64); gi += __shfl_xor(gi, 32, 64);
            gh += __shfl_xor(gh, 16, 64); gh += __shfl_xor(gh, 32, 64);
            gi3[g3] = gi; gh3[g3] = gh;
        }
        if (fin) {
            int j = jb + r;
            float gir = gi3[0] + bih1[j];
            float giz = gi3[1] + bih1[512 + j];
            float gin = gi3[2] + bih1[1024 + j];
            float ghr = gh3[0] + bhh1[j];
            float ghz = gh3[1] + bhh1[512 + j];
            float ghn = gh3[2] + bhh1[1024 + j];
            float r_ = sigf(gir + ghr);
            float z_ = sigf(giz + ghz);
            float n_ = tanhf(gin + r_ * ghn);
            float h1old = SB[bl * BLP + XIDX(j)];        // clipped prev h1
            float hn = (1.f - z_) * n_ + z_ * h1old;
            stA(&h1wr[bg * 512 + j], hn);                // preclip; clip on read
            comb[(size_t)(t * 32 + bg) * 1024 + j] = f2bf(hn);
        }
        gbar(barp, (++bcount) * 32);
    }
}

// ---------------- LDS-staged MFMA bf16 GEMM (128x128 tile, K-step 64) ----------------
// C[M,N] = A[M,K] * B[N,K]^T ; EPI 0: relu+bias -> bf16 (h1b); EPI 1: clip+bias -> f32 scatter (out)
template<int K, int EPI>
__global__ __launch_bounds__(256) void k_gemm(const unsigned short* __restrict__ A,
        const unsigned short* __restrict__ Bm, const float* __restrict__ bias,
        void* __restrict__ outp) {
    __shared__ unsigned short As[128][72];
    __shared__ unsigned short Bs[128][72];
    const int tid = threadIdx.x;
    const int wave = tid >> 6, lane = tid & 63;
    const int wm = wave >> 1, wn = wave & 1;
    const int m0 = blockIdx.y * 128, n0 = blockIdx.x * 128;
    const int m16 = lane & 15, q = lane >> 4;
    f32x4 acc[4][4];
    #pragma unroll
    for (int i = 0; i < 4; ++i)
        #pragma unroll
        for (int j = 0; j < 4; ++j) acc[i][j] = (f32x4){0.f, 0.f, 0.f, 0.f};

    for (int k0 = 0; k0 < K; k0 += 64) {
        __syncthreads();
        #pragma unroll
        for (int i = 0; i < 4; ++i) {
            int c = tid + i * 256;              // 1024 chunks of 8 bf16
            int row = c >> 3, c8 = c & 7;
            int ar = m0 + row; if (ar > NR - 1) ar = NR - 1;
            *(bf16x8*)&As[row][c8 * 8] = *(const bf16x8*)(A + (size_t)ar * K + k0 + c8 * 8);
            *(bf16x8*)&Bs[row][c8 * 8] = *(const bf16x8*)(Bm + (size_t)(n0 + row) * K + k0 + c8 * 8);
        }
        __syncthreads();
        #pragma unroll
        for (int kk = 0; kk < 64; kk += 32) {
            bf16x8 af[4], bfr[4];
            #pragma unroll
            for (int mi = 0; mi < 4; ++mi)
                af[mi] = *(const bf16x8*)&As[wm * 64 + mi * 16 + m16][kk + q * 8];
            #pragma unroll
            for (int ni = 0; ni < 4; ++ni)
                bfr[ni] = *(const bf16x8*)&Bs[wn * 64 + ni * 16 + m16][kk + q * 8];
            #pragma unroll
            for (int mi = 0; mi < 4; ++mi)
                #pragma unroll
                for (int ni = 0; ni < 4; ++ni)
                    acc[mi][ni] = __builtin_amdgcn_mfma_f32_16x16x32_bf16(af[mi], bfr[ni], acc[mi][ni], 0, 0, 0);
        }
    }
    #pragma unroll
    for (int mi = 0; mi < 4; ++mi)
        #pragma unroll
        for (int ni = 0; ni < 4; ++ni) {
            int n = n0 + wn * 64 + ni * 16 + m16;
            float bv = bias[n];
            #pragma unroll
            for (int rg = 0; rg < 4; ++rg) {
                int row = m0 + wm * 64 + mi * 16 + q * 4 + rg;
                if (row < NR) {
                    float v = acc[mi][ni][rg] + bv;
                    if (EPI == 0) {
                        v = fmaxf(v, 0.f);
                        ((unsigned short*)outp)[(size_t)row * 512 + n] = f2bf(v);
                    } else {
                        int tt = row >> 5, bb = row & 31;
                        v = clipf(v, -100.f, 100.f);
                        ((float*)outp)[(size_t)bb * T * V + (size_t)(tt + 1) * V + n] = v;
                    }
                }
            }
        }
}

// ---------------- launch ----------------

extern "C" void kernel_launch(void* const* d_in, const int* in_sizes, int n_in,
                              void* d_out, int out_size, void* d_ws, size_t ws_size,
                              hipStream_t stream) {
    const int*   tgt  = (const int*)d_in[0];
    const float* enc  = (const float*)d_in[1];
    const float* dec  = (const float*)d_in[2];
    const int*   mask = (const int*)d_in[3];
    const float* embt = (const float*)d_in[4];
    const float* wep  = (const float*)d_in[5];  const float* bep = (const float*)d_in[6];
    const float* wq   = (const float*)d_in[7];  const float* bq  = (const float*)d_in[8];
    const float* wk   = (const float*)d_in[9];  const float* bk  = (const float*)d_in[10];
    const float* wv   = (const float*)d_in[11]; const float* bv  = (const float*)d_in[12];
    const float* wo   = (const float*)d_in[13]; const float* bo  = (const float*)d_in[14];
    const float* wih0 = (const float*)d_in[15]; const float* whh0 = (const float*)d_in[16];
    const float* bih0 = (const float*)d_in[17]; const float* bhh0 = (const float*)d_in[18];
    const float* wih1 = (const float*)d_in[19]; const float* whh1 = (const float*)d_in[20];
    const float* bih1 = (const float*)d_in[21]; const float* bhh1 = (const float*)d_in[22];
    const float* wo1  = (const float*)d_in[23]; const float* bo1 = (const float*)d_in[24];
    const float* wo2  = (const float*)d_in[25]; const float* bo2 = (const float*)d_in[26];
    float* out = (float*)d_out;
    char* ws = (char*)d_ws;

    float* kht           = (float*)(ws + 0);            // 16 MB
    float* vh            = (float*)(ws + 16777216);     // 16 MB
    float* gie           = (float*)(ws + 33554432);     // 12.4 MB  [t*32+b][1536]
    unsigned short* comb = (unsigned short*)(ws + 45940736);  // 4.1 MB
    unsigned short* h1b  = (unsigned short*)(ws + 50069504);  // 2.1 MB
    unsigned short* w1b  = (unsigned short*)(ws + 52133888);  // 1 MB
    unsigned short* w2b  = (unsigned short*)(ws + 53182464);  // 32.8 MB
    float* ctx           = (float*)(ws + 85950464);     // 64 KB  [B][512]
    float* ctxo          = (float*)(ws + 86016000);     // 64 KB
    float* h0n           = (float*)(ws + 86081536);     // 128 KB [2][B][512]
    float* h1s           = (float*)(ws + 86212608);     // 128 KB [2][B][512]
    unsigned* bar        = (unsigned*)(ws + 86343680);  // 4 KB (8 groups x 256B)

    hipMemsetAsync(bar, 0, 4096, stream);
    hipLaunchKernelGGL(k_zero_t0, dim3(1000), dim3(256), 0, stream, out);
    hipLaunchKernelGGL(k_init_h, dim3(64), dim3(256), 0, stream, dec, h0n, h1s);
    hipLaunchKernelGGL(k_kv, dim3(B * S / 8), dim3(256), 0, stream, enc, wk, bk, wv, bv, kht, vh);
    hipLaunchKernelGGL(k_gie, dim3(NR / 8), dim3(256), 0, stream, tgt, embt, wep, bep, wih0, bih0, gie);
    hipLaunchKernelGGL(k_cvt, dim3(4096), dim3(256), 0, stream, wo1, wo2, w1b, w2b);
    hipLaunchKernelGGL(k_rec, dim3(256), dim3(256), 0, stream,
                       kht, vh, gie, mask, wq, bq, wo, bo,
                       wih0, whh0, bhh0, wih1, bih1, whh1, bhh1,
                       ctx, ctxo, h0n, h1s, comb, bar);
    hipLaunchKernelGGL(HIP_KERNEL_NAME(k_gemm<1024, 0>), dim3(4, 16), dim3(256), 0, stream,
                       comb, w1b, bo1, (void*)h1b);
    hipLaunchKernelGGL(HIP_KERNEL_NAME(k_gemm<512, 1>), dim3(250, 16), dim3(256), 0, stream,
                       h1b, w2b, bo2, (void*)out);
}

// Round 3
// 5193.203 us; speedup vs baseline: 2.0700x; 1.1331x over previous
//
#include <hip/hip_runtime.h>
#include <hip/hip_bf16.h>
#include <math.h>

#define B 32
#define T 64
#define S 256
#define H 512
#define E 256
#define V 32000
#define NH 8
#define HD 64
#define TS 63          // steps (T-1)
#define NR 2016        // TS*B rows
#define G3 1536        // 3*H

typedef short bf16x8 __attribute__((ext_vector_type(8)));
typedef float f32x4 __attribute__((ext_vector_type(4)));

__device__ __forceinline__ unsigned short f2bf(float f) {
    union { float f; unsigned u; } v; v.f = f;
    unsigned r = v.u + 0x7FFF + ((v.u >> 16) & 1);   // RNE
    return (unsigned short)(r >> 16);
}
__device__ __forceinline__ float clipf(float v, float lo, float hi) {
    return fminf(hi, fmaxf(lo, v));
}
__device__ __forceinline__ float sigf(float x) { return 1.0f / (1.0f + __expf(-x)); }

// agent-scope (coherence-point) accessors for cross-WG data inside k_rec
__device__ __forceinline__ void stA(float* p, float v) {
    __hip_atomic_store(p, v, __ATOMIC_RELAXED, __HIP_MEMORY_SCOPE_AGENT);
}
__device__ __forceinline__ unsigned long long ldA64(const void* p) {
    return __hip_atomic_load((const unsigned long long*)p, __ATOMIC_RELAXED, __HIP_MEMORY_SCOPE_AGENT);
}

// padded LDS segment layout: 128-float segments at pitch 132 (bank-spread partials)
#define XIDX(k) ((((k) >> 7) * 132) + ((k) & 127))
#define BLP 528   // per-batch pitch = 4*132

// ---------------- prolog kernels ----------------

__global__ void k_zero_t0(float* out) {
    int idx = blockIdx.x * 256 + threadIdx.x;        // over B*V/4
    int n = B * V / 4;
    if (idx < n) {
        int b = idx / (V / 4);
        int v4 = idx % (V / 4);
        float4* p = (float4*)(out + (size_t)b * T * V) + v4;
        *p = make_float4(0.f, 0.f, 0.f, 0.f);
    }
}

// writes initial state into parity-1 buffers of h0n / h1s ([2][B][512] row-major)
__global__ void k_init_h(const float* dec, float* h0n, float* h1s) {
    int i = blockIdx.x * 256 + threadIdx.x;
    if (i < B * H) {
        float v = clipf(dec[i], -10.f, 10.f);
        h0n[16384 + i] = v;
        h1s[16384 + i] = v;
    }
}

// K/V projections: 8 enc rows per WG so wk/wv stream 16x less from L2
__global__ __launch_bounds__(256) void k_kv(const float* __restrict__ enc,
        const float* __restrict__ wk, const float* __restrict__ bk,
        const float* __restrict__ wv, const float* __restrict__ bv,
        float* __restrict__ kht, float* __restrict__ vh) {
    __shared__ float x[8][512];
    int r0 = blockIdx.x * 8;
    for (int idx = threadIdx.x; idx < 4096; idx += 256) {
        int rr = idx >> 9, k = idx & 511;
        x[rr][k] = enc[(size_t)(r0 + rr) * 512 + k];
    }
    __syncthreads();
    int b = r0 >> 8, s0 = r0 & 255;
    for (int ii = 0; ii < 2; ++ii) {
        int i = threadIdx.x + ii * 256;
        const float* wkr = wk + (size_t)i * 512;
        const float* wvr = wv + (size_t)i * 512;
        float aK[8], aV[8];
        float bk0 = bk[i], bv0 = bv[i];
        #pragma unroll
        for (int rr = 0; rr < 8; ++rr) { aK[rr] = bk0; aV[rr] = bv0; }
        for (int k = 0; k < 512; k += 4) {
            float4 a = *(const float4*)(wkr + k);
            float4 c = *(const float4*)(wvr + k);
            #pragma unroll
            for (int rr = 0; rr < 8; ++rr) {
                float4 xv = *(const float4*)(&x[rr][k]);
                aK[rr] += a.x*xv.x + a.y*xv.y + a.z*xv.z + a.w*xv.w;
                aV[rr] += c.x*xv.x + c.y*xv.y + c.z*xv.z + c.w*xv.w;
            }
        }
        #pragma unroll
        for (int rr = 0; rr < 8; ++rr) {
            kht[((size_t)b * 512 + i) * 256 + s0 + rr] = clipf(aK[rr], -100.f, 100.f);
            vh[((size_t)b * 256 + s0 + rr) * 512 + i] = aV[rr];
        }
    }
}

// gie[(t*32+b)*1536 + j] = b_ih0[j] + emb(t,b) . w_ih0[j, 0:512]; 8 rows per WG
__global__ __launch_bounds__(256) void k_gie(const int* __restrict__ tgt,
        const float* __restrict__ embt, const float* __restrict__ wep,
        const float* __restrict__ bep, const float* __restrict__ wih0,
        const float* __restrict__ bih0, float* __restrict__ gie) {
    __shared__ float er[8][256];
    __shared__ float xf[8][512];
    int r0 = blockIdx.x * 8;
    for (int idx = threadIdx.x; idx < 2048; idx += 256) {
        int rr = idx >> 8, k = idx & 255;
        int rw = r0 + rr; int tt = rw >> 5, bb = rw & 31;
        er[rr][k] = embt[(size_t)tgt[bb * T + tt] * 256 + k];
    }
    __syncthreads();
    for (int ii = 0; ii < 2; ++ii) {
        int i = threadIdx.x + ii * 256;
        const float* wr = wep + (size_t)i * 256;
        float acc[8];
        float b0 = bep[i];
        #pragma unroll
        for (int rr = 0; rr < 8; ++rr) acc[rr] = b0;
        for (int k = 0; k < 256; k += 4) {
            float4 w4 = *(const float4*)(wr + k);
            #pragma unroll
            for (int rr = 0; rr < 8; ++rr) {
                float4 xv = *(const float4*)(&er[rr][k]);
                acc[rr] += w4.x*xv.x + w4.y*xv.y + w4.z*xv.z + w4.w*xv.w;
            }
        }
        #pragma unroll
        for (int rr = 0; rr < 8; ++rr) xf[rr][i] = acc[rr];
    }
    __syncthreads();
    for (int jj = 0; jj < 6; ++jj) {
        int j = threadIdx.x + jj * 256;
        const float* wr = wih0 + (size_t)j * 1024;   // emb part = cols 0..511
        float acc[8];
        float b0 = bih0[j];
        #pragma unroll
        for (int rr = 0; rr < 8; ++rr) acc[rr] = b0;
        for (int k = 0; k < 512; k += 4) {
            float4 w4 = *(const float4*)(wr + k);
            #pragma unroll
            for (int rr = 0; rr < 8; ++rr) {
                float4 xv = *(const float4*)(&xf[rr][k]);
                acc[rr] += w4.x*xv.x + w4.y*xv.y + w4.z*xv.z + w4.w*xv.w;
            }
        }
        #pragma unroll
        for (int rr = 0; rr < 8; ++rr) gie[(size_t)(r0 + rr) * 1536 + j] = acc[rr];
    }
}

__global__ void k_cvt(const float* __restrict__ wo1, const float* __restrict__ wo2,
                      unsigned short* __restrict__ w1b, unsigned short* __restrict__ w2b) {
    size_t idx = (size_t)blockIdx.x * 256 + threadIdx.x;
    size_t stride = (size_t)gridDim.x * 256;
    size_t n1 = (size_t)H * 2 * H;
    size_t n2 = (size_t)V * H;
    for (size_t i = idx; i < n1; i += stride) w1b[i] = f2bf(wo1[i]);
    for (size_t i = idx; i < n2; i += stride) w2b[i] = f2bf(wo2[i]);
}

// ---------------- persistent recurrence kernel ----------------
// 8 independent groups x 32 WGs; group g owns batches [4g, 4g+4).
// K/V for this WG's (batch, head) live in LDS for all 63 steps, so the
// per-XCD L2 holds only weights (~1.8 MB) -> L2-resident across phases.

__device__ __forceinline__ void gbar(unsigned* c, unsigned target) {
    __syncthreads();                 // drains vmcnt per wave before s_barrier
    if (threadIdx.x == 0) {
        asm volatile("s_waitcnt vmcnt(0)" ::: "memory");
        __hip_atomic_fetch_add(c, 1u, __ATOMIC_RELAXED, __HIP_MEMORY_SCOPE_AGENT);
        while (__hip_atomic_load(c, __ATOMIC_RELAXED, __HIP_MEMORY_SCOPE_AGENT) < target) {
            __builtin_amdgcn_s_sleep(1);
        }
    }
    __syncthreads();
}

// stage 4 batch-vectors (2048 floats) from global [4*512] into padded LDS [4][4][132]
__device__ __forceinline__ void stage4(float* dst, const float* src, bool doclip) {
    const unsigned long long* s = (const unsigned long long*)src;
    #pragma unroll
    for (int i = 0; i < 4; ++i) {
        int w = threadIdx.x + i * 256;        // 0..1023
        union { unsigned long long u; float f[2]; } c;
        c.u = ldA64(s + w);
        int bl = w >> 8;
        int k = (w & 255) * 2;
        float a = c.f[0], b2 = c.f[1];
        if (doclip) { a = clipf(a, -10.f, 10.f); b2 = clipf(b2, -10.f, 10.f); }
        int base = bl * BLP + XIDX(k);
        dst[base] = a; dst[base + 1] = b2;
    }
}

__device__ __forceinline__ float dot128(const float* __restrict__ w, const float* x) {
    float acc = 0.f;
    #pragma unroll 8
    for (int k = 0; k < 128; k += 4) {
        float4 a = *(const float4*)(w + k);
        acc += a.x * x[k] + a.y * x[k+1] + a.z * x[k+2] + a.w * x[k+3];
    }
    return acc;
}

__global__ __launch_bounds__(256, 1) void k_rec(
        const float* __restrict__ kht, const float* __restrict__ vh,
        const float* __restrict__ gie, const int* __restrict__ maskp,
        const float* __restrict__ wq,  const float* __restrict__ bq,
        const float* __restrict__ wo,  const float* __restrict__ bo,
        const float* __restrict__ wih0, const float* __restrict__ whh0, const float* __restrict__ bhh0,
        const float* __restrict__ wih1, const float* __restrict__ bih1,
        const float* __restrict__ whh1, const float* __restrict__ bhh1,
        float* __restrict__ ctx, float* __restrict__ ctxo,
        float* __restrict__ h0n, float* __restrict__ h1s,
        unsigned short* __restrict__ comb, unsigned* bar) {
    __shared__ float Kl[64][256];    // 64 KB: K[d][s] for this (ab, ah)
    __shared__ float Vl[256][64];    // 64 KB: V[s][d] for this (ab, ah)
    __shared__ float SA[4 * BLP];
    __shared__ float SB[4 * BLP];
    __shared__ float pq[256];
    __shared__ float qv[64];
    __shared__ float sc[256];
    __shared__ float cp[256];
    __shared__ float red[8];

    const int tid = threadIdx.x;
    const int wgid = blockIdx.x;
    const int grp = wgid >> 5;            // 0..7
    const int w = wgid & 31;              // 0..31 within group
    const int bg0 = grp * 4;              // first batch of group
    const int ab = bg0 + (w >> 3);        // phase A: batch
    const int ah = w & 7;                 // phase A: head
    const int jb = w * 16;                // row slab base for B/C/D
    const int bl = tid >> 6;              // wave index = local batch for B/C/D
    const int lane = tid & 63;
    const int r = lane & 15;
    const int p4 = lane >> 4;             // partial index 0..3
    const int bg = bg0 + bl;              // global batch for B/C/D
    const bool fin = (lane < 16);
    const int wid = tid >> 6;
    const bool apad = (maskp[ab * S + tid] == 0);
    unsigned* barp = bar + grp * 64;      // 256B-padded per-group counter
    unsigned bcount = 0;

    // ---- one-time K/V preload into LDS (reused for all 63 steps) ----
    {
        const float4* kb = (const float4*)(kht + ((size_t)ab * 512 + ah * 64) * 256);
        float4* kl = (float4*)&Kl[0][0];
        #pragma unroll
        for (int i = tid; i < 4096; i += 256) kl[i] = kb[i];
        #pragma unroll
        for (int i = tid; i < 4096; i += 256) {
            int s = i >> 4, dc = i & 15;
            float4 vv = *(const float4*)(vh + ((size_t)ab * 256 + s) * 512 + ah * 64 + dc * 4);
            *(float4*)&Vl[s][dc * 4] = vv;
        }
    }
    __syncthreads();

    for (int t = 0; t < TS; ++t) {
        const int par = t & 1;
        const float* h1rd = h1s + (par ^ 1) * 16384;
        float* h1wr = h1s + par * 16384;
        const float* h0rd = h0n + (par ^ 1) * 16384;
        float* h0wr = h0n + par * 16384;

        // ====== Phase A: attention for (ab, ah) ======
        {
            union { unsigned long long u; float f[2]; } c;
            c.u = ldA64((const unsigned long long*)(h1rd + ab * 512) + tid);
            int k2 = tid * 2;
            SA[XIDX(k2)]     = clipf(c.f[0], -10.f, 10.f);
            SA[XIDX(k2) + 1] = clipf(c.f[1], -10.f, 10.f);
        }
        __syncthreads();
        {   // q partials: f = tid>>2, p = tid&3  (wq rows L2-resident)
            int f = tid >> 2, p = tid & 3;
            pq[f * 4 + p] = dot128(wq + (size_t)(ah * 64 + f) * 512 + p * 128, SA + p * 132);
        }
        __syncthreads();
        if (tid < 64)
            qv[tid] = clipf(pq[tid*4] + pq[tid*4+1] + pq[tid*4+2] + pq[tid*4+3]
                            + bq[ah * 64 + tid], -100.f, 100.f);
        __syncthreads();
        {   // scores from LDS K: thread = s
            float acc = 0.f;
            #pragma unroll 8
            for (int d = 0; d < 64; ++d) acc += qv[d] * Kl[d][tid];
            sc[tid] = apad ? -10000.f : acc * 0.125f;
        }
        __syncthreads();
        {   // softmax over 256
            float v = sc[tid];
            float m = v;
            for (int o = 32; o >= 1; o >>= 1) m = fmaxf(m, __shfl_xor(m, o, 64));
            if ((tid & 63) == 0) red[wid] = m;
            __syncthreads();
            m = fmaxf(fmaxf(red[0], red[1]), fmaxf(red[2], red[3]));
            float e = __expf(v - m);
            float s = e;
            for (int o = 32; o >= 1; o >>= 1) s += __shfl_xor(s, o, 64);
            if ((tid & 63) == 0) red[4 + wid] = s;
            __syncthreads();
            float inv = 1.f / (red[4] + red[5] + red[6] + red[7]);
            sc[tid] = e * inv;
        }
        __syncthreads();
        {   // ctx partials from LDS V: d = tid&63, chunk c = tid>>6
            int d = tid & 63, cch = tid >> 6;
            float acc = 0.f;
            #pragma unroll 4
            for (int s2 = 0; s2 < 64; ++s2) acc += sc[cch * 64 + s2] * Vl[cch * 64 + s2][d];
            cp[tid] = acc;
        }
        __syncthreads();
        if (tid < 64)
            stA(&ctx[ab * 512 + ah * 64 + tid],
                cp[tid] + cp[64 + tid] + cp[128 + tid] + cp[192 + tid]);
        gbar(barp, (++bcount) * 32);

        // ====== Phase B: ctxo rows [jb, jb+16) for the group's 4 batches ======
        stage4(SA, ctx + bg0 * 512, false);
        __syncthreads();
        {
            float a = dot128(wo + (size_t)(jb + r) * 512 + p4 * 128, SA + bl * BLP + p4 * 132);
            a += __shfl_xor(a, 16, 64);
            a += __shfl_xor(a, 32, 64);
            if (fin) {
                int j = jb + r;
                float v = clipf(a + bo[j], -100.f, 100.f);
                stA(&ctxo[bg * 512 + j], v);
                comb[(size_t)(t * 32 + bg) * 1024 + 512 + j] = f2bf(v);
            }
        }
        gbar(barp, (++bcount) * 32);

        // ====== Phase C: GRU0 ======
        stage4(SA, ctxo + bg0 * 512, false);
        stage4(SB, h0rd + bg0 * 512, true);
        __syncthreads();
        float gi3[3], gh3[3];
        #pragma unroll
        for (int g3 = 0; g3 < 3; ++g3) {
            int row = g3 * 512 + jb + r;
            float gi = dot128(wih0 + (size_t)row * 1024 + 512 + p4 * 128, SA + bl * BLP + p4 * 132);
            float gh = dot128(whh0 + (size_t)row * 512 + p4 * 128, SB + bl * BLP + p4 * 132);
            gi += __shfl_xor(gi, 16, 64); gi += __shfl_xor(gi, 32, 64);
            gh += __shfl_xor(gh, 16, 64); gh += __shfl_xor(gh, 32, 64);
            gi3[g3] = gi; gh3[g3] = gh;
        }
        if (fin) {
            int j = jb + r;
            const float* gp = gie + (size_t)(t * 32 + bg) * 1536;
            float gir = gi3[0] + gp[j];
            float giz = gi3[1] + gp[512 + j];
            float gin = gi3[2] + gp[1024 + j];
            float ghr = gh3[0] + bhh0[j];
            float ghz = gh3[1] + bhh0[512 + j];
            float ghn = gh3[2] + bhh0[1024 + j];
            float r_ = sigf(gir + ghr);
            float z_ = sigf(giz + ghz);
            float n_ = tanhf(gin + r_ * ghn);
            float h0old = SB[bl * BLP + XIDX(j)];        // clipped prev h0
            float hn = (1.f - z_) * n_ + z_ * h0old;
            stA(&h0wr[bg * 512 + j], hn);                // preclip; clip on read
        }
        gbar(barp, (++bcount) * 32);

        // ====== Phase D: GRU1 ======
        stage4(SA, h0wr + bg0 * 512, false);             // h0 preclip (GRU1 input)
        stage4(SB, h1rd + bg0 * 512, true);              // h1 prev clipped
        __syncthreads();
        #pragma unroll
        for (int g3 = 0; g3 < 3; ++g3) {
            int row = g3 * 512 + jb + r;
            float gi = dot128(wih1 + (size_t)row * 512 + p4 * 128, SA + bl * BLP + p4 * 132);
            float gh = dot128(whh1 + (size_t)row * 512 + p4 * 128, SB + bl * BLP + p4 * 132);
            gi += __shfl_xor(gi, 16, 64); gi += __shfl_xor(gi, 32, 64);
            gh += __shfl_xor(gh, 16, 64); gh += __shfl_xor(gh, 32, 64);
            gi3[g3] = gi; gh3[g3] = gh;
        }
        if (fin) {
            int j = jb + r;
            float gir = gi3[0] + bih1[j];
            float giz = gi3[1] + bih1[512 + j];
            float gin = gi3[2] + bih1[1024 + j];
            float ghr = gh3[0] + bhh1[j];
            float ghz = gh3[1] + bhh1[512 + j];
            float ghn = gh3[2] + bhh1[1024 + j];
            float r_ = sigf(gir + ghr);
            float z_ = sigf(giz + ghz);
            float n_ = tanhf(gin + r_ * ghn);
            float h1old = SB[bl * BLP + XIDX(j)];        // clipped prev h1
            float hn = (1.f - z_) * n_ + z_ * h1old;
            stA(&h1wr[bg * 512 + j], hn);                // preclip; clip on read
            comb[(size_t)(t * 32 + bg) * 1024 + j] = f2bf(hn);
        }
        gbar(barp, (++bcount) * 32);
    }
}

// ---------------- MFMA bf16 GEMMs for output MLP ----------------
// k_g1: C[2016,512] = comb[2016,1024] @ w1b[512,1024]^T, relu+bias -> bf16
__global__ __launch_bounds__(256) void k_g1(const unsigned short* __restrict__ A,
        const unsigned short* __restrict__ Bm, const float* __restrict__ bias,
        unsigned short* __restrict__ outp) {
    __shared__ unsigned short As[128][72];
    __shared__ unsigned short Bs[128][72];
    const int tid = threadIdx.x;
    const int wave = tid >> 6, lane = tid & 63;
    const int wm = wave >> 1, wn = wave & 1;
    const int m0 = blockIdx.y * 128, n0 = blockIdx.x * 128;
    const int m16 = lane & 15, q = lane >> 4;
    f32x4 acc[4][4];
    #pragma unroll
    for (int i = 0; i < 4; ++i)
        #pragma unroll
        for (int j = 0; j < 4; ++j) acc[i][j] = (f32x4){0.f, 0.f, 0.f, 0.f};

    for (int k0 = 0; k0 < 1024; k0 += 64) {
        __syncthreads();
        #pragma unroll
        for (int i = 0; i < 4; ++i) {
            int c = tid + i * 256;
            int row = c >> 3, c8 = c & 7;
            int ar = m0 + row; if (ar > NR - 1) ar = NR - 1;
            *(bf16x8*)&As[row][c8 * 8] = *(const bf16x8*)(A + (size_t)ar * 1024 + k0 + c8 * 8);
            *(bf16x8*)&Bs[row][c8 * 8] = *(const bf16x8*)(Bm + (size_t)(n0 + row) * 1024 + k0 + c8 * 8);
        }
        __syncthreads();
        #pragma unroll
        for (int kk = 0; kk < 64; kk += 32) {
            bf16x8 af[4], bfr[4];
            #pragma unroll
            for (int mi = 0; mi < 4; ++mi)
                af[mi] = *(const bf16x8*)&As[wm * 64 + mi * 16 + m16][kk + q * 8];
            #pragma unroll
            for (int ni = 0; ni < 4; ++ni)
                bfr[ni] = *(const bf16x8*)&Bs[wn * 64 + ni * 16 + m16][kk + q * 8];
            #pragma unroll
            for (int mi = 0; mi < 4; ++mi)
                #pragma unroll
                for (int ni = 0; ni < 4; ++ni)
                    acc[mi][ni] = __builtin_amdgcn_mfma_f32_16x16x32_bf16(af[mi], bfr[ni], acc[mi][ni], 0, 0, 0);
        }
    }
    #pragma unroll
    for (int mi = 0; mi < 4; ++mi)
        #pragma unroll
        for (int ni = 0; ni < 4; ++ni) {
            int n = n0 + wn * 64 + ni * 16 + m16;
            float bv = bias[n];
            #pragma unroll
            for (int rg = 0; rg < 4; ++rg) {
                int row = m0 + wm * 64 + mi * 16 + q * 4 + rg;
                if (row < NR) {
                    float v = fmaxf(acc[mi][ni][rg] + bv, 0.f);
                    outp[(size_t)row * 512 + n] = f2bf(v);
                }
            }
        }
}

// k_g2: out = h1b[2016,512] @ w2b[32000,512]^T; full B-tile LDS-resident,
// loops all 16 m-tiles per WG -> w2b read exactly once (was 16x).
__global__ __launch_bounds__(256, 1) void k_g2(const unsigned short* __restrict__ h1b,
        const unsigned short* __restrict__ w2b, const float* __restrict__ b2,
        float* __restrict__ out) {
    __shared__ unsigned short Bs[128][520];   // 133 KB: full 128x512 B tile
    __shared__ unsigned short As[128][72];    // 18.4 KB: one 128x64 A k-slice
    const int tid = threadIdx.x;
    const int wave = tid >> 6, lane = tid & 63;
    const int wm = wave >> 1, wn = wave & 1;
    const int n0 = blockIdx.x * 128;
    const int m16 = lane & 15, q = lane >> 4;

    for (int i = tid; i < 128 * 64; i += 256) {        // 8192 chunks of 8 bf16
        int row = i >> 6, c8 = i & 63;
        *(bf16x8*)&Bs[row][c8 * 8] = *(const bf16x8*)(w2b + (size_t)(n0 + row) * 512 + c8 * 8);
    }

    for (int mt = 0; mt < 16; ++mt) {
        int m0 = mt * 128;
        f32x4 acc[4][4];
        #pragma unroll
        for (int i = 0; i < 4; ++i)
            #pragma unroll
            for (int j = 0; j < 4; ++j) acc[i][j] = (f32x4){0.f, 0.f, 0.f, 0.f};

        for (int k0 = 0; k0 < 512; k0 += 64) {
            __syncthreads();
            #pragma unroll
            for (int i = 0; i < 4; ++i) {
                int c = tid + i * 256;
                int row = c >> 3, c8 = c & 7;
                int ar = m0 + row; if (ar > NR - 1) ar = NR - 1;
                *(bf16x8*)&As[row][c8 * 8] = *(const bf16x8*)(h1b + (size_t)ar * 512 + k0 + c8 * 8);
            }
            __syncthreads();
            #pragma unroll
            for (int kk = 0; kk < 64; kk += 32) {
                bf16x8 af[4], bfr[4];
                #pragma unroll
                for (int mi = 0; mi < 4; ++mi)
                    af[mi] = *(const bf16x8*)&As[wm * 64 + mi * 16 + m16][kk + q * 8];
                #pragma unroll
                for (int ni = 0; ni < 4; ++ni)
                    bfr[ni] = *(const bf16x8*)&Bs[wn * 64 + ni * 16 + m16][k0 + kk + q * 8];
                #pragma unroll
                for (int mi = 0; mi < 4; ++mi)
                    #pragma unroll
                    for (int ni = 0; ni < 4; ++ni)
                        acc[mi][ni] = __builtin_amdgcn_mfma_f32_16x16x32_bf16(af[mi], bfr[ni], acc[mi][ni], 0, 0, 0);
            }
        }
        #pragma unroll
        for (int mi = 0; mi < 4; ++mi)
            #pragma unroll
            for (int ni = 0; ni < 4; ++ni) {
                int n = n0 + wn * 64 + ni * 16 + m16;
                float bv = b2[n];
                #pragma unroll
                for (int rg = 0; rg < 4; ++rg) {
                    int row = m0 + wm * 64 + mi * 16 + q * 4 + rg;
                    if (row < NR) {
                        int tt = row >> 5, bb = row & 31;
                        float v = clipf(acc[mi][ni][rg] + bv, -100.f, 100.f);
                        out[(size_t)bb * T * V + (size_t)(tt + 1) * V + n] = v;
                    }
                }
            }
    }
}

// ---------------- launch ----------------

extern "C" void kernel_launch(void* const* d_in, const int* in_sizes, int n_in,
                              void* d_out, int out_size, void* d_ws, size_t ws_size,
                              hipStream_t stream) {
    const int*   tgt  = (const int*)d_in[0];
    const float* enc  = (const float*)d_in[1];
    const float* dec  = (const float*)d_in[2];
    const int*   mask = (const int*)d_in[3];
    const float* embt = (const float*)d_in[4];
    const float* wep  = (const float*)d_in[5];  const float* bep = (const float*)d_in[6];
    const float* wq   = (const float*)d_in[7];  const float* bq  = (const float*)d_in[8];
    const float* wk   = (const float*)d_in[9];  const float* bk  = (const float*)d_in[10];
    const float* wv   = (const float*)d_in[11]; const float* bv  = (const float*)d_in[12];
    const float* wo   = (const float*)d_in[13]; const float* bo  = (const float*)d_in[14];
    const float* wih0 = (const float*)d_in[15]; const float* whh0 = (const float*)d_in[16];
    const float* bih0 = (const float*)d_in[17]; const float* bhh0 = (const float*)d_in[18];
    const float* wih1 = (const float*)d_in[19]; const float* whh1 = (const float*)d_in[20];
    const float* bih1 = (const float*)d_in[21]; const float* bhh1 = (const float*)d_in[22];
    const float* wo1  = (const float*)d_in[23]; const float* bo1 = (const float*)d_in[24];
    const float* wo2  = (const float*)d_in[25]; const float* bo2 = (const float*)d_in[26];
    float* out = (float*)d_out;
    char* ws = (char*)d_ws;

    float* kht           = (float*)(ws + 0);            // 16 MB
    float* vh            = (float*)(ws + 16777216);     // 16 MB
    float* gie           = (float*)(ws + 33554432);     // 12.4 MB  [t*32+b][1536]
    unsigned short* comb = (unsigned short*)(ws + 45940736);  // 4.1 MB
    unsigned short* h1b  = (unsigned short*)(ws + 50069504);  // 2.1 MB
    unsigned short* w1b  = (unsigned short*)(ws + 52133888);  // 1 MB
    unsigned short* w2b  = (unsigned short*)(ws + 53182464);  // 32.8 MB
    float* ctx           = (float*)(ws + 85950464);     // 64 KB  [B][512]
    float* ctxo          = (float*)(ws + 86016000);     // 64 KB
    float* h0n           = (float*)(ws + 86081536);     // 128 KB [2][B][512]
    float* h1s           = (float*)(ws + 86212608);     // 128 KB [2][B][512]
    unsigned* bar        = (unsigned*)(ws + 86343680);  // 4 KB (8 groups x 256B)

    hipMemsetAsync(bar, 0, 4096, stream);
    hipLaunchKernelGGL(k_zero_t0, dim3(1000), dim3(256), 0, stream, out);
    hipLaunchKernelGGL(k_init_h, dim3(64), dim3(256), 0, stream, dec, h0n, h1s);
    hipLaunchKernelGGL(k_kv, dim3(B * S / 8), dim3(256), 0, stream, enc, wk, bk, wv, bv, kht, vh);
    hipLaunchKernelGGL(k_gie, dim3(NR / 8), dim3(256), 0, stream, tgt, embt, wep, bep, wih0, bih0, gie);
    hipLaunchKernelGGL(k_cvt, dim3(4096), dim3(256), 0, stream, wo1, wo2, w1b, w2b);
    hipLaunchKernelGGL(k_rec, dim3(256), dim3(256), 0, stream,
                       kht, vh, gie, mask, wq, bq, wo, bo,
                       wih0, whh0, bhh0, wih1, bih1, whh1, bhh1,
                       ctx, ctxo, h0n, h1s, comb, bar);
    hipLaunchKernelGGL(k_g1, dim3(4, 16), dim3(256), 0, stream, comb, w1b, bo1, h1b);
    hipLaunchKernelGGL(k_g2, dim3(250), dim3(256), 0, stream, h1b, w2b, bo2, out);
}